// Round 7
// baseline (1457.902 us; speedup 1.0000x reference)
//
// Persistent clustered RNN for PQMatcher on gfx950.
// 256 blocks = 64 clusters (one per batch) x 4 blocks, 1024 threads each.
// ALL folded f16 weights in registers (a0-a9/b0-b9) as in R3..R6.
// R7: flagless sync. Every cross-block float is a (tag,value) u64 slot,
// written by ONE relaxed agent-scope b64 store (atomic visibility); consumers
// poll the slot until tag==step and get the value in the same load. This
// removes: separate flags, producer vmcnt-drain-before-post, and the
// detect->gather serialization (3 L3 RTs -> ~1.5 per sync). Monotonic tags
// make slot reuse safe (anti-overwrite verified via the cross-block dep
// chain: a producer reaching the phase that rewrites slot k of step i+1 has
// necessarily consumed every block's step-i data downstream of that slot).
// Exchanges: s-partials (4x128), gh (450), gi-partials (4x456).
// Structure per step: P1(tpre local sTV, gh->slots) | B'(s-partials->slots)
// | poll s+gh | C | CS | D(rg local) | E(gi->slots) | poll gi | F.
#include <hip/hip_runtime.h>
#include <hip/hip_fp16.h>

typedef _Float16 h2_t __attribute__((ext_vector_type(2)));
typedef unsigned long long u64;

__device__ __forceinline__ float dot2f(int w, int x, float acc) {
#if __has_builtin(__builtin_amdgcn_fdot2)
  return __builtin_amdgcn_fdot2(__builtin_bit_cast(h2_t, w),
                                __builtin_bit_cast(h2_t, x), acc, false);
#else
  h2_t a = __builtin_bit_cast(h2_t, w);
  h2_t b = __builtin_bit_cast(h2_t, x);
  return acc + (float)a[0] * (float)b[0] + (float)a[1] * (float)b[1];
#endif
}

__device__ __forceinline__ float rcp_f(float x) {
#if __has_builtin(__builtin_amdgcn_rcpf)
  return __builtin_amdgcn_rcpf(x);
#else
  return 1.0f / x;
#endif
}

__device__ __forceinline__ float fast_tanh(float x) {
  float e = exp2f(x * 2.885390082f);
  return 1.0f - 2.0f * rcp_f(e + 1.0f);
}
__device__ __forceinline__ float fast_sigmoid(float x) {
  return rcp_f(1.0f + exp2f(x * -1.442695041f));
}
__device__ __forceinline__ int packh2(float a, float b) {
  h2_t h;
  h[0] = (_Float16)a;
  h[1] = (_Float16)b;
  return __builtin_bit_cast(int, h);
}

// Coherent (agent-scope, relaxed) 8B accessors: no cache-maintenance ops.
__device__ __forceinline__ u64 ld64_coh(const u64* p) {
  return __hip_atomic_load((u64*)p, __ATOMIC_RELAXED, __HIP_MEMORY_SCOPE_AGENT);
}
__device__ __forceinline__ void st64_coh(u64* p, u64 v) {
  __hip_atomic_store(p, v, __ATOMIC_RELAXED, __HIP_MEMORY_SCOPE_AGENT);
}
__device__ __forceinline__ u64 packtv(float v, unsigned tag) {
  return ((u64)tag << 32) | (u64)__float_as_uint(v);
}
__device__ __forceinline__ float slotval(u64 v) {
  return __uint_as_float((unsigned)v);
}

__device__ __forceinline__ float poll1(const u64* p, unsigned tag) {
  u64 v;
  int spins = 0;
  for (;;) {
    v = ld64_coh(p);
    if ((unsigned)(v >> 32) == tag || ++spins >= (1 << 20)) break;
    __builtin_amdgcn_s_sleep(1);
  }
  return slotval(v);
}
__device__ __forceinline__ float poll4(const u64* p0, const u64* p1,
                                       const u64* p2, const u64* p3,
                                       unsigned tag) {
  float acc = 0.f;
  unsigned got = 0;
  int spins = 0;
  while (got != 15u && spins < (1 << 20)) {
    u64 v0 = 0, v1 = 0, v2 = 0, v3 = 0;
    if (!(got & 1u)) v0 = ld64_coh(p0);
    if (!(got & 2u)) v1 = ld64_coh(p1);
    if (!(got & 4u)) v2 = ld64_coh(p2);
    if (!(got & 8u)) v3 = ld64_coh(p3);
    if (!(got & 1u) && (unsigned)(v0 >> 32) == tag) { acc += slotval(v0); got |= 1u; }
    if (!(got & 2u) && (unsigned)(v1 >> 32) == tag) { acc += slotval(v1); got |= 2u; }
    if (!(got & 4u) && (unsigned)(v2 >> 32) == tag) { acc += slotval(v2); got |= 4u; }
    if (!(got & 8u) && (unsigned)(v3 >> 32) == tag) { acc += slotval(v3); got |= 8u; }
    ++spins;
    if (got != 15u) __builtin_amdgcn_s_sleep(1);
  }
  return acc;
}

#define DOTC(W, X, A)                                                          \
  {                                                                            \
    int4 _x = (X);                                                             \
    A = dot2f((W).x, _x.x, A);                                                 \
    A = dot2f((W).y, _x.y, A);                                                 \
    A = dot2f((W).z, _x.z, A);                                                 \
    A = dot2f((W).w, _x.w, A);                                                 \
  }

// ---------------------------------------------------------------------------
// Weight fold/transpose (unchanged layouts) + payload zeroing (tags start 0).
// ---------------------------------------------------------------------------
__global__ void prep_weights(const float* __restrict__ Wp,
                             const float* __restrict__ Wv,
                             const float* __restrict__ Wg,
                             const float* __restrict__ Wih,
                             const float* __restrict__ Whh,
                             __half* __restrict__ oMa, __half* __restrict__ oWg,
                             __half* __restrict__ oWih,
                             __half* __restrict__ oWhh,
                             int* __restrict__ payload) {
  int idx = blockIdx.x * 256 + threadIdx.x;
  if (idx < 393216) payload[idx] = 0;  // 64 clusters x 3072 u64 slots
  const int NMa = 150 * 304, NWg = 600 * 304, NWih = 900 * 304,
            NWhh = 452 * 152;
  if (idx < NMa) {
    int r = idx / 304, c = idx % 304;
    float v = 0.f;
    if (c < 150)
      v = Wp[r * 300 + c] + Wp[r * 300 + 150 + c];
    else if (c >= 152 && c < 302)
      v = Wv[r * 150 + (c - 152)];
    oMa[(c >> 3) * 1200 + r * 8 + (c & 7)] = __float2half(v);
    return;
  }
  idx -= NMa;
  if (idx < NWg) {
    int r = idx / 304, c = idx % 304;
    float v = 0.f;
    if (c < 150)
      v = Wg[r * 600 + c] + Wg[r * 600 + 150 + c];
    else if (c >= 152 && c < 302) {
      int d = c - 152;
      v = Wg[r * 600 + 300 + d] + Wg[r * 600 + 450 + d];
    }
    oWg[(c >> 3) * 4800 + r * 8 + (c & 7)] = __float2half(v);
    return;
  }
  idx -= NWg;
  if (idx < NWih) {
    int s = idx / 304, c = idx % 304;
    int r = s >> 1, off = (s & 1) * 300;
    float v = (c < 300) ? Wih[r * 600 + off + c] : 0.f;
    oWih[(c >> 3) * 7200 + s * 8 + (c & 7)] = __float2half(v);
    return;
  }
  idx -= NWih;
  if (idx < NWhh) {
    int r = idx / 152, c = idx % 152;
    float v = (r < 450 && c < 150) ? Whh[r * 150 + c] : 0.f;
    oWhh[(c >> 3) * 3616 + r * 8 + (c & 7)] = __float2half(v);
  }
}

// ---------------------------------------------------------------------------
// Prep 2: Wuq[b][l][h], Uqh[b][l][d]  (unchanged)
// ---------------------------------------------------------------------------
__global__ __launch_bounds__(256) void prep_wuq(const float* __restrict__ Uq,
                                                const float* __restrict__ Wq,
                                                __half* __restrict__ oWuq,
                                                __half* __restrict__ oUqh) {
  __shared__ float sUql[64 * 150];
  const int l = blockIdx.x, tid = threadIdx.x;
  for (int idx = tid; idx < 9600; idx += 256) sUql[idx] = Uq[l * 9600 + idx];
  __syncthreads();
  for (int idx = tid; idx < 64 * 152; idx += 256) {
    int bb = idx / 152, d = idx % 152;
    float v = (d < 150) ? sUql[bb * 150 + d] : 0.f;
    oUqh[(size_t)bb * 19456 + l * 152 + d] = __float2half(v);
  }
  if (tid < 152) {
    const int h = tid;
    if (h < 150) {
      float wq[150];
#pragma unroll
      for (int d = 0; d < 150; ++d)
        wq[d] = Wq[h * 300 + d] + Wq[h * 300 + 150 + d];
      for (int bb = 0; bb < 64; ++bb) {
        float acc = 0.f;
#pragma unroll
        for (int d = 0; d < 150; ++d) acc += wq[d] * sUql[bb * 150 + d];
        oWuq[(size_t)bb * 19456 + l * 152 + h] = __float2half(acc);
      }
    } else {
      for (int bb = 0; bb < 64; ++bb)
        oWuq[(size_t)bb * 19456 + l * 152 + h] = __float2half(0.f);
    }
  }
}

// ---------------------------------------------------------------------------
__global__ __launch_bounds__(1024, 1) void pq_main(
    const float* __restrict__ Up, const float* __restrict__ V,
    const float* __restrict__ v0, const float* __restrict__ b_ih,
    const float* __restrict__ b_hh, const int* __restrict__ gWuq,
    const __half* __restrict__ gUqh, const int* __restrict__ gMa,
    const int* __restrict__ gWg, const int* __restrict__ gWih,
    const int* __restrict__ gWhh, u64* __restrict__ payload,
    float* __restrict__ out) {
  __shared__ __align__(16) float sTV[304];
  __shared__ __align__(16) float sV[152];
  __shared__ __align__(16) float sGh[456];
  __shared__ __align__(16) float sS[128];
  __shared__ __align__(16) float sSS[4];
  __shared__ __align__(16) float sC0[152];
  __shared__ __align__(16) float sCp[608];
  __shared__ __align__(16) float sU[152];
  __shared__ __align__(16) float sv_[152];
  __shared__ __align__(16) int sXd[152];
  __shared__ __align__(16) int svh[76];
  __shared__ __align__(16) int sRgh[304];
  __shared__ __align__(16) float sGi[456];
  __shared__ __align__(16) float sBih[456];
  __shared__ __align__(16) float sBhh[456];
  extern __shared__ __align__(16) int dynlds[];
  int* sWuq = dynlds;                       // 9728 ints (38,912 B)
  __half* sUqh = (__half*)(dynlds + 9728);  // 19456 halves (38,912 B)

  const int t = threadIdx.x;
  const int c = blockIdx.x & 63;  // cluster == batch
  const int q = blockIdx.x >> 6;  // quarter within cluster
  const int b = c;

  u64* pl = payload + (size_t)c * 3072;
  u64* sSlot = pl;          // s-partials: q*128 + l      -> [0,512)
  u64* ghSlot = pl + 512;   // gh: r                      -> [512,962)
  u64* giSlot = pl + 1024;  // gi partials: q*456 + r     -> [1024,2848)

  const int4* MaT4 = (const int4*)gMa;
  const int4* WgT4 = (const int4*)gWg;
  const int4* WihT4 = (const int4*)gWih;
  const int4* WhhT4 = (const int4*)gWhh;

  const int baseR = 113 * q - (q == 3 ? 1 : 0);  // 0,113,226,338
  const int cntR = (q < 2) ? 113 : 112;
  // Wih column-split chunk range for this quarter (packed-halves space)
  const int c_lo = (q == 0) ? 0 : (q == 1) ? 18 : (q == 2) ? 38 : 56;
  const int c_hi = (q == 0) ? 18 : (q == 1) ? 37 : (q == 2) ? 56 : 75;

  // ---- load ALL owned weight chunks into registers ----
  int4 a0, a1, a2, a3, a4, a5, a6, a7, a8, a9;
  int4 b0, b1, b2, b3, b4, b5, b6, b7, b8, b9;
  {
    const int4* p;
    int nr, sub, step, nch, row;
    if (t < 152) {  // Ma rows 38q+rl, 4 lanes/row
      p = MaT4; nr = 150; step = 4; nch = 38;
      sub = t & 3; row = 38 * q + (t >> 2);
      if (row > 149) row = 149;
    } else if (t < 378) {  // Whh rows baseR+rl, 2 lanes/row
      p = WhhT4; nr = 452; step = 2; nch = 19;
      int u2 = t - 152; sub = u2 & 1; row = baseR + (u2 >> 1);
    } else if (t >= 384 && t < 984) {  // Wg rows 150q+rl, 4 lanes/row
      p = WgT4; nr = 600; step = 4; nch = 38;
      int u2 = t - 384; sub = u2 & 3; row = 150 * q + (u2 >> 2);
    } else {
      p = MaT4; nr = 150; step = 4; nch = 38; sub = 0; row = 0;
    }
#define LDA(i)                                                                 \
  {                                                                            \
    int cc = sub + step * (i);                                                 \
    if (cc > nch - 1) cc = nch - 1;                                            \
    a##i = p[cc * nr + row];                                                   \
  }
    LDA(0) LDA(1) LDA(2) LDA(3) LDA(4) LDA(5) LDA(6) LDA(7) LDA(8) LDA(9)
#undef LDA
  }
  {
    // Wih COLUMN split: all 450 rows, chunks c_lo+sub+2k (k<10), 2 lanes/row
    int row = (t < 900) ? (t >> 1) : 0;
    int sub = (t < 900) ? (t & 1) : 0;
#define LDB(i)                                                                 \
  {                                                                            \
    int cq = c_lo + sub + 2 * (i);                                             \
    if (cq > c_hi) cq = c_hi;                                                  \
    int hf = (cq >= 38) ? 1 : 0;                                               \
    int cc = cq - 38 * hf;                                                     \
    b##i = WihT4[cc * 900 + 2 * row + hf];                                     \
  }
    LDB(0) LDB(1) LDB(2) LDB(3) LDB(4) LDB(5) LDB(6) LDB(7) LDB(8) LDB(9)
#undef LDB
  }

  // ---- LDS init: Wuq + Uqh resident, state vectors, biases ----
  for (int idx = t; idx < 9728; idx += 1024) sWuq[idx] = gWuq[b * 9728 + idx];
  {
    const int* gU2 = (const int*)(gUqh + (size_t)b * 19456);
    int* sU2 = (int*)sUqh;
    for (int idx = t; idx < 9728; idx += 1024) sU2[idx] = gU2[idx];
  }
  if (t < 150) {
    sV[t] = V[b * 150 + t];
    float v_ = v0[b * 150 + t];
    sv_[t] = v_;
    float vn = __shfl_down(v_, 1);
    if (!(t & 1)) svh[t >> 1] = packh2(v_, vn);
    float u_ = Up[b * 150 + t];
    sU[t] = u_;
    float un = __shfl_down(u_, 1);
    if (!(t & 1)) sXd[t >> 1] = packh2(u_, un);
  }
  for (int idx = t; idx < 450; idx += 1024) {
    sBih[idx] = b_ih[idx];
    sBhh[idx] = b_hh[idx];
  }
  if (t < 304) {
    sRgh[t] = 0;   // non-owned halves must stay zero (column split)
    sTV[t] = 0.f;  // unwritten tv slots
  }
  if (t == 0) {
    svh[75] = 0;
    sXd[75] = 0;
    sXd[151] = 0;
    sV[150] = 0.f;
    sV[151] = 0.f;
  }
  const int4* sXd4 = (const int4*)sXd;
  const int4* svh4 = (const int4*)svh;
  const int4* sRgh4 = (const int4*)sRgh;
  const int c_lq = t / 150;
  const int c_d0 = t - c_lq * 150;
  __syncthreads();

#pragma unroll 1
  for (int i = 0; i < 128; ++i) {
    const unsigned tagv = (unsigned)(i + 1);
    float unext = 0.f;
    if (t >= 640 && t < 790) {
      int ii = (i < 127) ? (i + 1) : 127;
      unext = Up[ii * 9600 + b * 150 + (t - 640)];
    }

    // ---- Phase 1: tpre quarter -> LOCAL sTV (t<152) || gh -> tagged slots
    if (t < 152) {
      int rl = t >> 2, sub = t & 3;
      float acc0 = 0.f, acc1 = 0.f;
#define MAD(i2, A)                                                             \
  {                                                                            \
    int cc = sub + 4 * (i2);                                                   \
    if (cc < 38) {                                                             \
      int4 x = (cc < 19) ? sXd4[cc] : svh4[cc - 19];                           \
      DOTC(a##i2, x, A)                                                        \
    }                                                                          \
  }
      MAD(0, acc0) MAD(1, acc1) MAD(2, acc0) MAD(3, acc1) MAD(4, acc0)
      MAD(5, acc1) MAD(6, acc0) MAD(7, acc1) MAD(8, acc0) MAD(9, acc1)
#undef MAD
      float acc = acc0 + acc1;
      acc += __shfl_xor(acc, 1);
      acc += __shfl_xor(acc, 2);
      float accN = __shfl_down(acc, 4);  // tpre of rl+1 (same wave: rl even)
      if (sub == 0 && !(rl & 1)) {
        int w = 19 * q + (rl >> 1);
        int h = 38 * q + rl;
        float4 tv;
        tv.x = acc;
        tv.y = accN;
        tv.z = sV[h];
        tv.w = sV[h + 1];
        ((float4*)sTV)[w] = tv;
      }
    } else if (t < 378) {
      int u2 = t - 152;
      int rl = u2 >> 1, sub = u2 & 1;
      int r = baseR + rl;
      float acc0 = 0.f, acc1 = 0.f;
#define HHD(i2, A)                                                             \
  {                                                                            \
    int cc = sub + 2 * (i2);                                                   \
    if (cc < 19) DOTC(a##i2, svh4[cc], A)                                      \
  }
      HHD(0, acc0) HHD(1, acc1) HHD(2, acc0) HHD(3, acc1) HHD(4, acc0)
      HHD(5, acc1) HHD(6, acc0) HHD(7, acc1) HHD(8, acc0) HHD(9, acc1)
#undef HHD
      float acc = acc0 + acc1;
      acc += __shfl_xor(acc, 1);
      if (sub == 0 && rl < cntR)
        st64_coh(&ghSlot[r], packtv(acc + sBhh[r], tagv));
    }
    __syncthreads();

    // ---- Phase B' (quarter): s_l^q over OWN 19 w-slots -> tagged slots
    {
      const int l = t >> 3, sub = t & 7;
      const int base = l * 76;
      float acc = 0.f;
#pragma unroll
      for (int k = 0; k < 3; ++k) {
        int wl = sub + 8 * k;
        if (wl < 19) {
          int w = 19 * q + wl;
          int qq = sWuq[base + w];
          float4 tv = ((const float4*)sTV)[w];
          h2_t hq = __builtin_bit_cast(h2_t, qq);
          float x0 = (float)hq[0] + tv.x;
          float x1 = (float)hq[1] + tv.y;
          acc += fast_tanh(x0) * tv.z;
          acc += fast_tanh(x1) * tv.w;
        }
      }
      acc += __shfl_xor(acc, 1);
      acc += __shfl_xor(acc, 2);
      acc += __shfl_xor(acc, 4);
      if (sub == 0) st64_coh(&sSlot[128 * q + l], packtv(acc, tagv));
    }

    // ---- POLL-1: s = sum of 4 tagged partials -> exp; gh -> sGh
    if (t < 128) {
      float s = poll4(&sSlot[t], &sSlot[128 + t], &sSlot[256 + t],
                      &sSlot[384 + t], tagv);
      sS[t] = exp2f(s * 1.442695041f);
    } else if (t >= 128 && t < 578) {
      sGh[t - 128] = poll1(&ghSlot[t - 128], tagv);
    }
    __syncthreads();

    // ---- Phase C (replicated): c0 raw partials; wave 15 computes S=sum(e)
    if (t < 600) {
      const __half* src = sUqh + c_lq * 32 * 152 + c_d0;
      float acc = 0.f;
#pragma unroll
      for (int j = 0; j < 32; ++j) {
        float a = sS[c_lq * 32 + j];
        acc += a * __half2float(src[j * 152]);
      }
      sCp[c_lq * 152 + c_d0] = acc;
    } else if (t >= 960) {
      int lane = t - 960;
      float e = sS[lane] + sS[64 + lane];
#pragma unroll
      for (int o = 1; o < 64; o <<= 1) e += __shfl_xor(e, o);
      if (lane == 0) sSS[0] = e;
    }
    __syncthreads();
    // ---- Phase CS: c0 = (sum of raw partials) * rcp(S)
    if (t < 150) {
      float inv = rcp_f(sSS[0]);
      float c0 = (sCp[t] + sCp[152 + t] + sCp[304 + t] + sCp[456 + t]) * inv;
      sC0[t] = c0;
      float cn = __shfl_down(c0, 1);
      if (!(t & 1)) sXd[76 + (t >> 1)] = packh2(c0, cn);
    }
    __syncthreads();

    // ---- Phase D: rg quarter (t in [384,984)) -- LOCAL, into sRgh halves
    if (t >= 384 && t < 984) {
      int u2 = t - 384;
      int rl = u2 >> 2, sub = u2 & 3;
      int j = 150 * q + rl;
      float acc0 = 0.f, acc1 = 0.f;
#define WGD(i2, A)                                                             \
  {                                                                            \
    int cc = sub + 4 * (i2);                                                   \
    if (cc < 38) DOTC(a##i2, sXd4[cc], A)                                      \
  }
      WGD(0, acc0) WGD(1, acc1) WGD(2, acc0) WGD(3, acc1) WGD(4, acc0)
      WGD(5, acc1) WGD(6, acc0) WGD(7, acc1) WGD(8, acc0) WGD(9, acc1)
#undef WGD
      float acc = acc0 + acc1;
      acc += __shfl_xor(acc, 1);
      acc += __shfl_xor(acc, 2);
      if (sub == 0) {
        float rb;
        if (j < 150)
          rb = sU[j];
        else if (j < 300)
          rb = sU[j - 150];
        else if (j < 450)
          rb = sC0[j - 300];
        else
          rb = sC0[j - 450];
        float rg = rb * fast_sigmoid(acc);
        ((__half*)sRgh)[(j < 300) ? j : (j + 4)] = __float2half(rg);
      }
    }
    __syncthreads();

    // ---- Phase E: PARTIAL gi over this quarter's Wih columns -> tagged slots
    if (t < 900) {
      int row = t >> 1, sub = t & 1;
      float acc0 = 0.f, acc1 = 0.f;
#define IHD(i2, A)                                                             \
  {                                                                            \
    int cq = c_lo + sub + 2 * (i2);                                            \
    if (cq <= c_hi) DOTC(b##i2, sRgh4[cq], A)                                  \
  }
      IHD(0, acc0) IHD(1, acc1) IHD(2, acc0) IHD(3, acc1) IHD(4, acc0)
      IHD(5, acc1) IHD(6, acc0) IHD(7, acc1) IHD(8, acc0) IHD(9, acc1)
#undef IHD
      float acc = acc0 + acc1;
      acc += __shfl_xor(acc, 1);
      if (!sub) st64_coh(&giSlot[456 * q + row], packtv(acc, tagv));
    }
    // ---- POLL-2: gi = sum of 4 tagged partials + bias (no barrier needed
    //      before the polls; they are per-thread independent)
    if (t < 450) {
      float g = poll4(&giSlot[t], &giSlot[456 + t], &giSlot[912 + t],
                      &giSlot[1368 + t], tagv);
      sGi[t] = g + sBih[t];
    }
    __syncthreads();

    // ---- Phase F (replicated): GRU update; q==0 stores out; stage next u
    if (t < 150) {
      float ir = sGi[t], iz = sGi[150 + t], in_ = sGi[300 + t];
      float hr = sGh[t], hz = sGh[150 + t], hn = sGh[300 + t];
      float rr = fast_sigmoid(ir + hr);
      float zz = fast_sigmoid(iz + hz);
      float nn = fast_tanh(in_ + rr * hn);
      float vold = sv_[t];
      float hv = nn + zz * (vold - nn);
      if (q == 0) out[i * 9600 + b * 150 + t] = hv;
      sv_[t] = hv;
      float hv1 = __shfl_down(hv, 1);
      if (!(t & 1)) svh[t >> 1] = packh2(hv, hv1);
    } else if (t >= 640 && t < 790) {
      int t2 = t - 640;
      sU[t2] = unext;
      float un = __shfl_down(unext, 1);
      if (!(t2 & 1)) sXd[t2 >> 1] = packh2(unext, un);
    }
    __syncthreads();
  }
}

// ---------------------------------------------------------------------------
extern "C" void kernel_launch(void* const* d_in, const int* in_sizes, int n_in,
                              void* d_out, int out_size, void* d_ws,
                              size_t ws_size, hipStream_t stream) {
  const float* Up = (const float*)d_in[0];
  const float* Uq = (const float*)d_in[1];
  const float* Wp = (const float*)d_in[2];
  const float* Wq = (const float*)d_in[3];
  const float* Wv = (const float*)d_in[4];
  const float* Wg = (const float*)d_in[5];
  const float* V = (const float*)d_in[6];
  const float* v0 = (const float*)d_in[7];
  const float* Wih = (const float*)d_in[8];
  const float* Whh = (const float*)d_in[9];
  const float* bih = (const float*)d_in[10];
  const float* bhh = (const float*)d_in[11];

  char* ws = (char*)d_ws;
  __half* wsWuq = (__half*)(ws);            // 2,490,368 B
  __half* wsUqh = (__half*)(ws + 2490368);  // 2,490,368 B
  __half* wsMa = (__half*)(ws + 4980736);   //    91,200 B
  __half* wsWg = (__half*)(ws + 5071936);   //   364,800 B
  __half* wsWih = (__half*)(ws + 5436736);  //   547,200 B
  __half* wsWhh = (__half*)(ws + 5983936);  //   137,408 B
  u64* wsPayload = (u64*)(ws + 6121472);    // 1,572,864 B (64 x 3072 u64)

  (void)hipFuncSetAttribute((const void*)pq_main,
                            hipFuncAttributeMaxDynamicSharedMemorySize, 77824);

  prep_weights<<<2228, 256, 0, stream>>>(Wp, Wv, Wg, Wih, Whh, wsMa, wsWg,
                                         wsWih, wsWhh, (int*)wsPayload);
  prep_wuq<<<128, 256, 0, stream>>>(Uq, Wq, wsWuq, wsUqh);
  pq_main<<<256, 1024, 77824, stream>>>(Up, V, v0, bih, bhh, (const int*)wsWuq,
                                        wsUqh, (const int*)wsMa,
                                        (const int*)wsWg, (const int*)wsWih,
                                        (const int*)wsWhh, wsPayload,
                                        (float*)d_out);
}